// Round 1
// baseline (3084.670 us; speedup 1.0000x reference)
//
#include <hip/hip_runtime.h>

#define N_RET  200000
#define N_ORIG 100000
#define N_EDGE 800000

// ---------------- degree histogram ----------------
__global__ void deg_kernel(const int* __restrict__ ridx,
                           const int* __restrict__ cidx,
                           float* __restrict__ dret,
                           float* __restrict__ dorig) {
    int e = blockIdx.x * blockDim.x + threadIdx.x;
    if (e < N_EDGE) {
        atomicAdd(&dret[ridx[e]], 1.0f);
        atomicAdd(&dorig[cidx[e]], 1.0f);
    }
}

// ---------------- edge scatter: dst[didx[e]] += src[sidx[e]] (rows of 128 f32) ----------------
__global__ void scatter_rows(const float4* __restrict__ src,
                             const int* __restrict__ sidx,
                             const int* __restrict__ didx,
                             float* __restrict__ dst) {
    int t = blockIdx.x * blockDim.x + threadIdx.x;
    int e = t >> 5;                 // 32 threads (one float4 lane each) per edge
    if (e >= N_EDGE) return;
    int d4 = t & 31;
    float4 v = src[(size_t)sidx[e] * 32 + d4];
    float* p = dst + (size_t)didx[e] * 128 + (d4 << 2);
    atomicAdd(p + 0, v.x);
    atomicAdd(p + 1, v.y);
    atomicAdd(p + 2, v.z);
    atomicAdd(p + 3, v.w);
}

// ---------------- GEMM 1: r1s = relu(agg_scaled @ Wl + x_ret @ Wr + bl) * inv_s ----------------
// 64 rows x 128 cols per block, 256 threads, 8x4 micro-tile. In-place (out == agg buffer).
__global__ __launch_bounds__(256) void
gemm_r1(const float4* __restrict__ agg4, const float4* __restrict__ xret4,
        const float4* __restrict__ Wl4, const float4* __restrict__ Wr4,
        const float4* __restrict__ bl4, const float* __restrict__ deg,
        float4* __restrict__ out4) {
    __shared__ float4 Ast[32][17];   // [kk][row-quad], transposed A tile, padded
    __shared__ float4 Ws4[32][32];   // [kk][col-quad]

    const int t  = threadIdx.x;
    const int cg = t & 31;           // col quad: cols cg*4..cg*4+3
    const int rg = t >> 5;           // row group: rows rg*8..rg*8+7
    const int i0 = blockIdx.x * 64;

    const int f4c = t & 7;           // k-quad within BK=32
    const int ar  = t >> 3;          // loader row 0..31 (+32 on second pass)

    float acc[8][4];
    #pragma unroll
    for (int i = 0; i < 8; ++i)
        #pragma unroll
        for (int j = 0; j < 4; ++j) acc[i][j] = 0.f;

    const float rdiv0 = 1.0f / fmaxf(deg[i0 + ar], 1.0f);
    const float rdiv1 = 1.0f / fmaxf(deg[i0 + ar + 32], 1.0f);

    #pragma unroll
    for (int phase = 0; phase < 2; ++phase) {
        const float4* A4 = phase ? xret4 : agg4;
        const float4* W4 = phase ? Wr4 : Wl4;
        for (int k0 = 0; k0 < 128; k0 += 32) {
            // A tile -> LDS (transposed, scalar scatter)
            #pragma unroll
            for (int pass = 0; pass < 2; ++pass) {
                int m = ar + pass * 32;
                float4 v = A4[(size_t)(i0 + m) * 32 + (k0 >> 2) + f4c];
                if (phase == 0) {
                    float s = pass ? rdiv1 : rdiv0;
                    v.x *= s; v.y *= s; v.z *= s; v.w *= s;
                }
                int base = ((m >> 2) << 2) + (m & 3);
                ((float*)Ast)[(f4c * 4 + 0) * 68 + base] = v.x;
                ((float*)Ast)[(f4c * 4 + 1) * 68 + base] = v.y;
                ((float*)Ast)[(f4c * 4 + 2) * 68 + base] = v.z;
                ((float*)Ast)[(f4c * 4 + 3) * 68 + base] = v.w;
            }
            // W tile -> LDS
            #pragma unroll
            for (int wr = 0; wr < 4; ++wr) {
                int kk = (t >> 5) + wr * 8;
                Ws4[kk][cg] = W4[(size_t)(k0 + kk) * 32 + cg];
            }
            __syncthreads();
            #pragma unroll
            for (int kk = 0; kk < 32; ++kk) {
                float4 a0 = Ast[kk][rg * 2];
                float4 a1 = Ast[kk][rg * 2 + 1];
                float4 w  = Ws4[kk][cg];
                const float* aa0 = (const float*)&a0;
                const float* aa1 = (const float*)&a1;
                const float* ww  = (const float*)&w;
                #pragma unroll
                for (int i = 0; i < 4; ++i)
                    #pragma unroll
                    for (int j = 0; j < 4; ++j) {
                        acc[i][j]     = fmaf(aa0[i], ww[j], acc[i][j]);
                        acc[i + 4][j] = fmaf(aa1[i], ww[j], acc[i + 4][j]);
                    }
            }
            __syncthreads();
        }
    }

    float4 blv = bl4[cg];
    const float* blp = (const float*)&blv;
    #pragma unroll
    for (int i = 0; i < 8; ++i) {
        int gi = i0 + rg * 8 + i;
        float dg = deg[gi];
        float sinv = dg > 0.f ? rsqrtf(dg) : 0.f;
        float4 o;
        o.x = fmaxf(acc[i][0] + blp[0], 0.f) * sinv;
        o.y = fmaxf(acc[i][1] + blp[1], 0.f) * sinv;
        o.z = fmaxf(acc[i][2] + blp[2], 0.f) * sinv;
        o.w = fmaxf(acc[i][3] + blp[3], 0.f) * sinv;
        out4[(size_t)gi * 32 + cg] = o;
    }
}

// ---------------- GEMM 2: h2s = r1s @ Wg (plain, in-place) ----------------
__global__ __launch_bounds__(256) void
gemm_h2(const float4* __restrict__ in4, const float4* __restrict__ Wg4,
        float4* __restrict__ out4) {
    __shared__ float4 Ast[32][17];
    __shared__ float4 Ws4[32][32];

    const int t  = threadIdx.x;
    const int cg = t & 31;
    const int rg = t >> 5;
    const int i0 = blockIdx.x * 64;
    const int f4c = t & 7;
    const int ar  = t >> 3;

    float acc[8][4];
    #pragma unroll
    for (int i = 0; i < 8; ++i)
        #pragma unroll
        for (int j = 0; j < 4; ++j) acc[i][j] = 0.f;

    for (int k0 = 0; k0 < 128; k0 += 32) {
        #pragma unroll
        for (int pass = 0; pass < 2; ++pass) {
            int m = ar + pass * 32;
            float4 v = in4[(size_t)(i0 + m) * 32 + (k0 >> 2) + f4c];
            int base = ((m >> 2) << 2) + (m & 3);
            ((float*)Ast)[(f4c * 4 + 0) * 68 + base] = v.x;
            ((float*)Ast)[(f4c * 4 + 1) * 68 + base] = v.y;
            ((float*)Ast)[(f4c * 4 + 2) * 68 + base] = v.z;
            ((float*)Ast)[(f4c * 4 + 3) * 68 + base] = v.w;
        }
        #pragma unroll
        for (int wr = 0; wr < 4; ++wr) {
            int kk = (t >> 5) + wr * 8;
            Ws4[kk][cg] = Wg4[(size_t)(k0 + kk) * 32 + cg];
        }
        __syncthreads();
        #pragma unroll
        for (int kk = 0; kk < 32; ++kk) {
            float4 a0 = Ast[kk][rg * 2];
            float4 a1 = Ast[kk][rg * 2 + 1];
            float4 w  = Ws4[kk][cg];
            const float* aa0 = (const float*)&a0;
            const float* aa1 = (const float*)&a1;
            const float* ww  = (const float*)&w;
            #pragma unroll
            for (int i = 0; i < 4; ++i)
                #pragma unroll
                for (int j = 0; j < 4; ++j) {
                    acc[i][j]     = fmaf(aa0[i], ww[j], acc[i][j]);
                    acc[i + 4][j] = fmaf(aa1[i], ww[j], acc[i + 4][j]);
                }
        }
        __syncthreads();
    }

    #pragma unroll
    for (int i = 0; i < 8; ++i) {
        int gi = i0 + rg * 8 + i;
        float4 o;
        o.x = acc[i][0]; o.y = acc[i][1]; o.z = acc[i][2]; o.w = acc[i][3];
        out4[(size_t)gi * 32 + cg] = o;
    }
}

// ---------------- GEMM 3: out = relu(acc*inv_d + b_g2) @ W_out + b_out ----------------
// M=100000 (guarded), K=128, N=64. 64x64 tile per block, 4x4 micro-tile.
__global__ __launch_bounds__(256) void
gemm_out(const float4* __restrict__ acc4, const float* __restrict__ degd,
         const float4* __restrict__ bg4, const float4* __restrict__ Wo4,
         const float4* __restrict__ bo4, float4* __restrict__ out4) {
    __shared__ float4 Ast[32][17];
    __shared__ float4 Ws[32][16];

    const int t  = threadIdx.x;
    const int cg = t & 15;           // col quad: cols cg*4..+3 (64 cols)
    const int rg = t >> 4;           // 0..15, rows rg*4..+3
    const int i0 = blockIdx.x * 64;
    const int f4c = t & 7;
    const int ar  = t >> 3;

    float acc[4][4];
    #pragma unroll
    for (int i = 0; i < 4; ++i)
        #pragma unroll
        for (int j = 0; j < 4; ++j) acc[i][j] = 0.f;

    int gr0 = min(i0 + ar, N_ORIG - 1);
    int gr1 = min(i0 + ar + 32, N_ORIG - 1);
    float dg0 = degd[gr0], dg1 = degd[gr1];
    float di0 = dg0 > 0.f ? rsqrtf(dg0) : 0.f;
    float di1 = dg1 > 0.f ? rsqrtf(dg1) : 0.f;

    for (int k0 = 0; k0 < 128; k0 += 32) {
        float4 bg = bg4[(k0 >> 2) + f4c];
        #pragma unroll
        for (int pass = 0; pass < 2; ++pass) {
            int m = ar + pass * 32;
            int gi = pass ? gr1 : gr0;
            float di = pass ? di1 : di0;
            float4 v = acc4[(size_t)gi * 32 + (k0 >> 2) + f4c];
            v.x = fmaxf(fmaf(v.x, di, bg.x), 0.f);
            v.y = fmaxf(fmaf(v.y, di, bg.y), 0.f);
            v.z = fmaxf(fmaf(v.z, di, bg.z), 0.f);
            v.w = fmaxf(fmaf(v.w, di, bg.w), 0.f);
            int base = ((m >> 2) << 2) + (m & 3);
            ((float*)Ast)[(f4c * 4 + 0) * 68 + base] = v.x;
            ((float*)Ast)[(f4c * 4 + 1) * 68 + base] = v.y;
            ((float*)Ast)[(f4c * 4 + 2) * 68 + base] = v.z;
            ((float*)Ast)[(f4c * 4 + 3) * 68 + base] = v.w;
        }
        #pragma unroll
        for (int wr = 0; wr < 2; ++wr) {
            int kk = (t >> 4) + wr * 16;
            Ws[kk][cg] = Wo4[(size_t)(k0 + kk) * 16 + cg];
        }
        __syncthreads();
        #pragma unroll
        for (int kk = 0; kk < 32; ++kk) {
            float4 a = Ast[kk][rg];
            float4 w = Ws[kk][cg];
            const float* aa = (const float*)&a;
            const float* ww = (const float*)&w;
            #pragma unroll
            for (int i = 0; i < 4; ++i)
                #pragma unroll
                for (int j = 0; j < 4; ++j)
                    acc[i][j] = fmaf(aa[i], ww[j], acc[i][j]);
        }
        __syncthreads();
    }

    float4 bo = bo4[cg];
    const float* bop = (const float*)&bo;
    #pragma unroll
    for (int i = 0; i < 4; ++i) {
        int gi = i0 + rg * 4 + i;
        if (gi < N_ORIG) {
            float4 o;
            o.x = acc[i][0] + bop[0];
            o.y = acc[i][1] + bop[1];
            o.z = acc[i][2] + bop[2];
            o.w = acc[i][3] + bop[3];
            out4[(size_t)gi * 16 + cg] = o;
        }
    }
}

extern "C" void kernel_launch(void* const* d_in, const int* in_sizes, int n_in,
                              void* d_out, int out_size, void* d_ws, size_t ws_size,
                              hipStream_t stream) {
    const float* x_ret    = (const float*)d_in[0];
    const float* x_orig   = (const float*)d_in[1];
    const int*   ret_idx  = (const int*)d_in[2];
    const int*   orig_idx = (const int*)d_in[3];
    // d_in[4] W_g1, d_in[5] b_g1: dead (o1 unused by the output)
    const float* Wl1  = (const float*)d_in[6];
    const float* bl1  = (const float*)d_in[7];
    const float* Wr1  = (const float*)d_in[8];
    const float* Wg2  = (const float*)d_in[9];
    const float* bg2  = (const float*)d_in[10];
    // d_in[11..13] Wl2, bl2, Wr2: dead (r2 unused by the output)
    const float* Wout = (const float*)d_in[14];
    const float* bout = (const float*)d_in[15];
    float* out = (float*)d_out;

    // workspace layout (all f32):
    //   big      : N_RET*128   (agg -> r1s -> h2s, updated in place by row-block GEMMs)
    //   acc      : N_ORIG*128  (GCN edge accumulator)
    //   deg_ret  : N_RET
    //   deg_orig : N_ORIG
    float* big      = (float*)d_ws;
    float* accb     = big + (size_t)N_RET * 128;
    float* deg_ret  = accb + (size_t)N_ORIG * 128;
    float* deg_orig = deg_ret + N_RET;

    hipMemsetAsync(big,  0, (size_t)N_RET * 128 * sizeof(float), stream);
    hipMemsetAsync(accb, 0, (size_t)N_ORIG * 128 * sizeof(float), stream);
    hipMemsetAsync(deg_ret, 0, (size_t)(N_RET + N_ORIG) * sizeof(float), stream);

    deg_kernel<<<(N_EDGE + 255) / 256, 256, 0, stream>>>(ret_idx, orig_idx, deg_ret, deg_orig);

    // agg[r] += x_orig[orig_idx[e]]  scattered to ret_idx[e]
    scatter_rows<<<(N_EDGE * 32) / 256, 256, 0, stream>>>(
        (const float4*)x_orig, orig_idx, ret_idx, big);

    // r1s = relu(agg/max(deg,1) @ Wl1 + x_ret @ Wr1 + bl1) * inv_s   (in place)
    gemm_r1<<<N_RET / 64, 256, 0, stream>>>(
        (const float4*)big, (const float4*)x_ret, (const float4*)Wl1,
        (const float4*)Wr1, (const float4*)bl1, deg_ret, (float4*)big);

    // h2s = r1s @ W_g2   (in place)
    gemm_h2<<<N_RET / 64, 256, 0, stream>>>(
        (const float4*)big, (const float4*)Wg2, (float4*)big);

    // acc[c] += h2s[ret_idx[e]]  scattered to orig_idx[e]
    scatter_rows<<<(N_EDGE * 32) / 256, 256, 0, stream>>>(
        (const float4*)big, ret_idx, orig_idx, accb);

    // out = relu(acc*inv_d + b_g2) @ W_out + b_out
    gemm_out<<<(N_ORIG + 63) / 64, 256, 0, stream>>>(
        (const float4*)accb, deg_orig, (const float4*)bg2,
        (const float4*)Wout, (const float4*)bout, (float4*)out);
}

// Round 2
// 648.421 us; speedup vs baseline: 4.7572x; 4.7572x over previous
//
#include <hip/hip_runtime.h>

#define N_RET  200000
#define N_ORIG 100000
#define N_EDGE 800000

#define SCAN_ELEMS 2048   // elements per scan1 block (256 thr * 8)

// ---------------- int degree histogram ----------------
__global__ void count_kernel(const int* __restrict__ ridx,
                             const int* __restrict__ cidx,
                             int* __restrict__ cret,
                             int* __restrict__ corig) {
    int e = blockIdx.x * blockDim.x + threadIdx.x;
    if (e < N_EDGE) {
        atomicAdd(&cret[ridx[e]], 1);
        atomicAdd(&corig[cidx[e]], 1);
    }
}

// ---------------- scan stage 1: per-block exclusive scan + block sums ----------------
__global__ __launch_bounds__(256) void scan1(const int* __restrict__ cnt,
                                             int* __restrict__ off,
                                             int* __restrict__ bsum, int n) {
    __shared__ int sm[256];
    int t = threadIdx.x;
    int base = blockIdx.x * SCAN_ELEMS;
    int loc[8];
    int s = 0;
    #pragma unroll
    for (int i = 0; i < 8; ++i) {
        int idx = base + t * 8 + i;
        int v = (idx < n) ? cnt[idx] : 0;
        loc[i] = s;
        s += v;
    }
    sm[t] = s;
    __syncthreads();
    for (int d = 1; d < 256; d <<= 1) {
        int v = (t >= d) ? sm[t - d] : 0;
        __syncthreads();
        sm[t] += v;
        __syncthreads();
    }
    int tbase = (t > 0) ? sm[t - 1] : 0;
    #pragma unroll
    for (int i = 0; i < 8; ++i) {
        int idx = base + t * 8 + i;
        if (idx < n) off[idx] = tbase + loc[i];
    }
    if (t == 255) bsum[blockIdx.x] = sm[255];
}

// ---------------- scan stage 2: single-block exclusive scan of block sums ----------------
__global__ __launch_bounds__(256) void scan2(int* __restrict__ bsum, int nb) {
    __shared__ int sm[256];
    int t = threadIdx.x;
    int v = (t < nb) ? bsum[t] : 0;
    sm[t] = v;
    __syncthreads();
    for (int d = 1; d < 256; d <<= 1) {
        int u = (t >= d) ? sm[t - d] : 0;
        __syncthreads();
        sm[t] += u;
        __syncthreads();
    }
    if (t < nb) bsum[t] = sm[t] - v;
}

// ---------------- scan stage 3: add block offsets; write offsets + cursors ----------------
__global__ void scan3(int* __restrict__ off, int* __restrict__ cur,
                      const int* __restrict__ bsum, int n) {
    int i = blockIdx.x * blockDim.x + threadIdx.x;
    if (i < n) {
        int v = off[i] + bsum[i >> 11];   // 2048 = SCAN_ELEMS
        off[i] = v;
        cur[i] = v;
    }
    if (i == 0) off[n] = N_EDGE;
}

// ---------------- CSR fill: elist holds SOURCE node ids, grouped by dst ----------------
__global__ void fill_kernel(const int* __restrict__ ridx,
                            const int* __restrict__ cidx,
                            int* __restrict__ cur_ret, int* __restrict__ cur_orig,
                            int* __restrict__ el1, int* __restrict__ el2) {
    int e = blockIdx.x * blockDim.x + threadIdx.x;
    if (e < N_EDGE) {
        int r = ridx[e], c = cidx[e];
        int p1 = atomicAdd(&cur_ret[r], 1);  el1[p1] = c;   // dst=ret,  src=orig
        int p2 = atomicAdd(&cur_orig[c], 1); el2[p2] = r;   // dst=orig, src=ret
    }
}

// ---------------- gather: dst[node] = sum over edge list of src rows (128 f32) ----------------
__global__ void gather_rows(const float4* __restrict__ src,
                            const int* __restrict__ off,
                            const int* __restrict__ slist,
                            float4* __restrict__ dst, int n_dst) {
    int t = blockIdx.x * blockDim.x + threadIdx.x;
    int node = t >> 5;              // 32 threads per node, one float4 each
    if (node >= n_dst) return;
    int d4 = t & 31;
    int s = off[node], e = off[node + 1];
    float4 acc = {0.f, 0.f, 0.f, 0.f};
    for (int i = s; i < e; ++i) {
        int sn = slist[i];
        float4 v = src[(size_t)sn * 32 + d4];
        acc.x += v.x; acc.y += v.y; acc.z += v.z; acc.w += v.w;
    }
    dst[(size_t)node * 32 + d4] = acc;
}

// ---------------- GEMM 1: r1s = relu(agg/max(deg,1) @ Wl + x_ret @ Wr + bl) * inv_s ----------------
__global__ __launch_bounds__(256) void
gemm_r1(const float4* __restrict__ agg4, const float4* __restrict__ xret4,
        const float4* __restrict__ Wl4, const float4* __restrict__ Wr4,
        const float4* __restrict__ bl4, const int* __restrict__ deg,
        float4* __restrict__ out4) {
    __shared__ float4 Ast[32][17];
    __shared__ float4 Ws4[32][32];

    const int t  = threadIdx.x;
    const int cg = t & 31;
    const int rg = t >> 5;
    const int i0 = blockIdx.x * 64;
    const int f4c = t & 7;
    const int ar  = t >> 3;

    float acc[8][4];
    #pragma unroll
    for (int i = 0; i < 8; ++i)
        #pragma unroll
        for (int j = 0; j < 4; ++j) acc[i][j] = 0.f;

    const float rdiv0 = 1.0f / fmaxf((float)deg[i0 + ar], 1.0f);
    const float rdiv1 = 1.0f / fmaxf((float)deg[i0 + ar + 32], 1.0f);

    #pragma unroll
    for (int phase = 0; phase < 2; ++phase) {
        const float4* A4 = phase ? xret4 : agg4;
        const float4* W4 = phase ? Wr4 : Wl4;
        for (int k0 = 0; k0 < 128; k0 += 32) {
            #pragma unroll
            for (int pass = 0; pass < 2; ++pass) {
                int m = ar + pass * 32;
                float4 v = A4[(size_t)(i0 + m) * 32 + (k0 >> 2) + f4c];
                if (phase == 0) {
                    float s = pass ? rdiv1 : rdiv0;
                    v.x *= s; v.y *= s; v.z *= s; v.w *= s;
                }
                int base = ((m >> 2) << 2) + (m & 3);
                ((float*)Ast)[(f4c * 4 + 0) * 68 + base] = v.x;
                ((float*)Ast)[(f4c * 4 + 1) * 68 + base] = v.y;
                ((float*)Ast)[(f4c * 4 + 2) * 68 + base] = v.z;
                ((float*)Ast)[(f4c * 4 + 3) * 68 + base] = v.w;
            }
            #pragma unroll
            for (int wr = 0; wr < 4; ++wr) {
                int kk = (t >> 5) + wr * 8;
                Ws4[kk][cg] = W4[(size_t)(k0 + kk) * 32 + cg];
            }
            __syncthreads();
            #pragma unroll
            for (int kk = 0; kk < 32; ++kk) {
                float4 a0 = Ast[kk][rg * 2];
                float4 a1 = Ast[kk][rg * 2 + 1];
                float4 w  = Ws4[kk][cg];
                const float* aa0 = (const float*)&a0;
                const float* aa1 = (const float*)&a1;
                const float* ww  = (const float*)&w;
                #pragma unroll
                for (int i = 0; i < 4; ++i)
                    #pragma unroll
                    for (int j = 0; j < 4; ++j) {
                        acc[i][j]     = fmaf(aa0[i], ww[j], acc[i][j]);
                        acc[i + 4][j] = fmaf(aa1[i], ww[j], acc[i + 4][j]);
                    }
            }
            __syncthreads();
        }
    }

    float4 blv = bl4[cg];
    const float* blp = (const float*)&blv;
    #pragma unroll
    for (int i = 0; i < 8; ++i) {
        int gi = i0 + rg * 8 + i;
        float dg = (float)deg[gi];
        float sinv = dg > 0.f ? rsqrtf(dg) : 0.f;
        float4 o;
        o.x = fmaxf(acc[i][0] + blp[0], 0.f) * sinv;
        o.y = fmaxf(acc[i][1] + blp[1], 0.f) * sinv;
        o.z = fmaxf(acc[i][2] + blp[2], 0.f) * sinv;
        o.w = fmaxf(acc[i][3] + blp[3], 0.f) * sinv;
        out4[(size_t)gi * 32 + cg] = o;
    }
}

// ---------------- GEMM 2: h2s = r1s @ Wg (in-place) ----------------
__global__ __launch_bounds__(256) void
gemm_h2(const float4* __restrict__ in4, const float4* __restrict__ Wg4,
        float4* __restrict__ out4) {
    __shared__ float4 Ast[32][17];
    __shared__ float4 Ws4[32][32];

    const int t  = threadIdx.x;
    const int cg = t & 31;
    const int rg = t >> 5;
    const int i0 = blockIdx.x * 64;
    const int f4c = t & 7;
    const int ar  = t >> 3;

    float acc[8][4];
    #pragma unroll
    for (int i = 0; i < 8; ++i)
        #pragma unroll
        for (int j = 0; j < 4; ++j) acc[i][j] = 0.f;

    for (int k0 = 0; k0 < 128; k0 += 32) {
        #pragma unroll
        for (int pass = 0; pass < 2; ++pass) {
            int m = ar + pass * 32;
            float4 v = in4[(size_t)(i0 + m) * 32 + (k0 >> 2) + f4c];
            int base = ((m >> 2) << 2) + (m & 3);
            ((float*)Ast)[(f4c * 4 + 0) * 68 + base] = v.x;
            ((float*)Ast)[(f4c * 4 + 1) * 68 + base] = v.y;
            ((float*)Ast)[(f4c * 4 + 2) * 68 + base] = v.z;
            ((float*)Ast)[(f4c * 4 + 3) * 68 + base] = v.w;
        }
        #pragma unroll
        for (int wr = 0; wr < 4; ++wr) {
            int kk = (t >> 5) + wr * 8;
            Ws4[kk][cg] = Wg4[(size_t)(k0 + kk) * 32 + cg];
        }
        __syncthreads();
        #pragma unroll
        for (int kk = 0; kk < 32; ++kk) {
            float4 a0 = Ast[kk][rg * 2];
            float4 a1 = Ast[kk][rg * 2 + 1];
            float4 w  = Ws4[kk][cg];
            const float* aa0 = (const float*)&a0;
            const float* aa1 = (const float*)&a1;
            const float* ww  = (const float*)&w;
            #pragma unroll
            for (int i = 0; i < 4; ++i)
                #pragma unroll
                for (int j = 0; j < 4; ++j) {
                    acc[i][j]     = fmaf(aa0[i], ww[j], acc[i][j]);
                    acc[i + 4][j] = fmaf(aa1[i], ww[j], acc[i + 4][j]);
                }
        }
        __syncthreads();
    }

    #pragma unroll
    for (int i = 0; i < 8; ++i) {
        int gi = i0 + rg * 8 + i;
        float4 o;
        o.x = acc[i][0]; o.y = acc[i][1]; o.z = acc[i][2]; o.w = acc[i][3];
        out4[(size_t)gi * 32 + cg] = o;
    }
}

// ---------------- GEMM 3: out = relu(acc*inv_d + b_g2) @ W_out + b_out ----------------
__global__ __launch_bounds__(256) void
gemm_out(const float4* __restrict__ acc4, const int* __restrict__ degd,
         const float4* __restrict__ bg4, const float4* __restrict__ Wo4,
         const float4* __restrict__ bo4, float4* __restrict__ out4) {
    __shared__ float4 Ast[32][17];
    __shared__ float4 Ws[32][16];

    const int t  = threadIdx.x;
    const int cg = t & 15;
    const int rg = t >> 4;
    const int i0 = blockIdx.x * 64;
    const int f4c = t & 7;
    const int ar  = t >> 3;

    float acc[4][4];
    #pragma unroll
    for (int i = 0; i < 4; ++i)
        #pragma unroll
        for (int j = 0; j < 4; ++j) acc[i][j] = 0.f;

    int gr0 = min(i0 + ar, N_ORIG - 1);
    int gr1 = min(i0 + ar + 32, N_ORIG - 1);
    float dg0 = (float)degd[gr0], dg1 = (float)degd[gr1];
    float di0 = dg0 > 0.f ? rsqrtf(dg0) : 0.f;
    float di1 = dg1 > 0.f ? rsqrtf(dg1) : 0.f;

    for (int k0 = 0; k0 < 128; k0 += 32) {
        float4 bg = bg4[(k0 >> 2) + f4c];
        #pragma unroll
        for (int pass = 0; pass < 2; ++pass) {
            int m = ar + pass * 32;
            int gi = pass ? gr1 : gr0;
            float di = pass ? di1 : di0;
            float4 v = acc4[(size_t)gi * 32 + (k0 >> 2) + f4c];
            v.x = fmaxf(fmaf(v.x, di, bg.x), 0.f);
            v.y = fmaxf(fmaf(v.y, di, bg.y), 0.f);
            v.z = fmaxf(fmaf(v.z, di, bg.z), 0.f);
            v.w = fmaxf(fmaf(v.w, di, bg.w), 0.f);
            int base = ((m >> 2) << 2) + (m & 3);
            ((float*)Ast)[(f4c * 4 + 0) * 68 + base] = v.x;
            ((float*)Ast)[(f4c * 4 + 1) * 68 + base] = v.y;
            ((float*)Ast)[(f4c * 4 + 2) * 68 + base] = v.z;
            ((float*)Ast)[(f4c * 4 + 3) * 68 + base] = v.w;
        }
        #pragma unroll
        for (int wr = 0; wr < 2; ++wr) {
            int kk = (t >> 4) + wr * 16;
            Ws[kk][cg] = Wo4[(size_t)(k0 + kk) * 16 + cg];
        }
        __syncthreads();
        #pragma unroll
        for (int kk = 0; kk < 32; ++kk) {
            float4 a = Ast[kk][rg];
            float4 w = Ws[kk][cg];
            const float* aa = (const float*)&a;
            const float* ww = (const float*)&w;
            #pragma unroll
            for (int i = 0; i < 4; ++i)
                #pragma unroll
                for (int j = 0; j < 4; ++j)
                    acc[i][j] = fmaf(aa[i], ww[j], acc[i][j]);
        }
        __syncthreads();
    }

    float4 bo = bo4[cg];
    const float* bop = (const float*)&bo;
    #pragma unroll
    for (int i = 0; i < 4; ++i) {
        int gi = i0 + rg * 4 + i;
        if (gi < N_ORIG) {
            float4 o;
            o.x = acc[i][0] + bop[0];
            o.y = acc[i][1] + bop[1];
            o.z = acc[i][2] + bop[2];
            o.w = acc[i][3] + bop[3];
            out4[(size_t)gi * 16 + cg] = o;
        }
    }
}

extern "C" void kernel_launch(void* const* d_in, const int* in_sizes, int n_in,
                              void* d_out, int out_size, void* d_ws, size_t ws_size,
                              hipStream_t stream) {
    const float* x_ret    = (const float*)d_in[0];
    const float* x_orig   = (const float*)d_in[1];
    const int*   ret_idx  = (const int*)d_in[2];
    const int*   orig_idx = (const int*)d_in[3];
    const float* Wl1  = (const float*)d_in[6];
    const float* bl1  = (const float*)d_in[7];
    const float* Wr1  = (const float*)d_in[8];
    const float* Wg2  = (const float*)d_in[9];
    const float* bg2  = (const float*)d_in[10];
    const float* Wout = (const float*)d_in[14];
    const float* bout = (const float*)d_in[15];
    float* out = (float*)d_out;

    // workspace layout
    float* big      = (float*)d_ws;                        // N_RET*128  (agg -> r1s -> h2s)
    float* accb     = big + (size_t)N_RET * 128;           // N_ORIG*128 (GCN2 accumulator)
    int*   cnt_ret  = (int*)(accb + (size_t)N_ORIG * 128); // N_RET
    int*   cnt_orig = cnt_ret + N_RET;                     // N_ORIG
    int*   off_ret  = cnt_orig + N_ORIG;                   // N_RET+1
    int*   off_orig = off_ret + N_RET + 1;                 // N_ORIG+1
    int*   cur_ret  = off_orig + N_ORIG + 1;               // N_RET
    int*   cur_orig = cur_ret + N_RET;                     // N_ORIG
    int*   bsum1    = cur_orig + N_ORIG;                   // 256
    int*   bsum2    = bsum1 + 256;                         // 256
    int*   el1      = bsum2 + 256;                         // N_EDGE (src=orig, grouped by ret)
    int*   el2      = el1 + N_EDGE;                        // N_EDGE (src=ret, grouped by orig)

    hipMemsetAsync(cnt_ret, 0, (size_t)(N_RET + N_ORIG) * sizeof(int), stream);

    count_kernel<<<(N_EDGE + 255) / 256, 256, 0, stream>>>(ret_idx, orig_idx, cnt_ret, cnt_orig);

    const int nb_ret  = (N_RET  + SCAN_ELEMS - 1) / SCAN_ELEMS;   // 98
    const int nb_orig = (N_ORIG + SCAN_ELEMS - 1) / SCAN_ELEMS;   // 49
    scan1<<<nb_ret,  256, 0, stream>>>(cnt_ret,  off_ret,  bsum1, N_RET);
    scan1<<<nb_orig, 256, 0, stream>>>(cnt_orig, off_orig, bsum2, N_ORIG);
    scan2<<<1, 256, 0, stream>>>(bsum1, nb_ret);
    scan2<<<1, 256, 0, stream>>>(bsum2, nb_orig);
    scan3<<<(N_RET  + 255) / 256, 256, 0, stream>>>(off_ret,  cur_ret,  bsum1, N_RET);
    scan3<<<(N_ORIG + 255) / 256, 256, 0, stream>>>(off_orig, cur_orig, bsum2, N_ORIG);

    fill_kernel<<<(N_EDGE + 255) / 256, 256, 0, stream>>>(ret_idx, orig_idx,
                                                          cur_ret, cur_orig, el1, el2);

    // agg[r] = sum of x_orig rows over edges with dst=r
    gather_rows<<<(N_RET * 32) / 256, 256, 0, stream>>>(
        (const float4*)x_orig, off_ret, el1, (float4*)big, N_RET);

    gemm_r1<<<N_RET / 64, 256, 0, stream>>>(
        (const float4*)big, (const float4*)x_ret, (const float4*)Wl1,
        (const float4*)Wr1, (const float4*)bl1, cnt_ret, (float4*)big);

    gemm_h2<<<N_RET / 64, 256, 0, stream>>>(
        (const float4*)big, (const float4*)Wg2, (float4*)big);

    // acc[c] = sum of h2s rows over edges with dst=c
    gather_rows<<<(N_ORIG * 32) / 256, 256, 0, stream>>>(
        (const float4*)big, off_orig, el2, (float4*)accb, N_ORIG);

    gemm_out<<<(N_ORIG + 63) / 64, 256, 0, stream>>>(
        (const float4*)accb, cnt_orig, (const float4*)bg2,
        (const float4*)Wout, (const float4*)bout, (float4*)out);
}

// Round 3
// 384.604 us; speedup vs baseline: 8.0204x; 1.6859x over previous
//
#include <hip/hip_runtime.h>

#define N_RET  200000
#define N_ORIG 100000
#define N_EDGE 800000
#define SCAN_ELEMS 2048

typedef __attribute__((ext_vector_type(8))) short bf16x8;   // 8 bf16 (4 VGPRs)
typedef __attribute__((ext_vector_type(4))) float f32x4;    // MFMA C/D

__device__ __forceinline__ ushort f2bf(float f) {
    union { float f; unsigned u; } v; v.f = f;
    unsigned r = v.u + 0x7FFFu + ((v.u >> 16) & 1u);   // RNE
    return (ushort)(r >> 16);
}
__device__ __forceinline__ float bf2f(ushort u) {
    union { unsigned u; float f; } v; v.u = ((unsigned)u) << 16;
    return v.f;
}

// ---------------- weight transpose + bf16 convert: WT[n][k] = bf16(W[k][n]) ----------------
__global__ void wt_kernel(const float* __restrict__ W, ushort* __restrict__ WT,
                          int total, int nshift) {
    int i = blockIdx.x * 256 + threadIdx.x;
    if (i >= total) return;
    int N = 1 << nshift;
    int k = i >> nshift, n = i & (N - 1);
    int K = total >> nshift;
    WT[n * K + k] = f2bf(W[i]);
}

// ---------------- CSR build ----------------
__global__ void count_kernel(const int* __restrict__ ridx, const int* __restrict__ cidx,
                             int* __restrict__ cret, int* __restrict__ corig) {
    int e = blockIdx.x * blockDim.x + threadIdx.x;
    if (e < N_EDGE) {
        atomicAdd(&cret[ridx[e]], 1);
        atomicAdd(&corig[cidx[e]], 1);
    }
}

__global__ __launch_bounds__(256) void scan1(const int* __restrict__ cnt,
                                             int* __restrict__ off,
                                             int* __restrict__ bsum, int n) {
    __shared__ int sm[256];
    int t = threadIdx.x;
    int base = blockIdx.x * SCAN_ELEMS;
    int loc[8];
    int s = 0;
    #pragma unroll
    for (int i = 0; i < 8; ++i) {
        int idx = base + t * 8 + i;
        int v = (idx < n) ? cnt[idx] : 0;
        loc[i] = s;
        s += v;
    }
    sm[t] = s;
    __syncthreads();
    for (int d = 1; d < 256; d <<= 1) {
        int v = (t >= d) ? sm[t - d] : 0;
        __syncthreads();
        sm[t] += v;
        __syncthreads();
    }
    int tbase = (t > 0) ? sm[t - 1] : 0;
    #pragma unroll
    for (int i = 0; i < 8; ++i) {
        int idx = base + t * 8 + i;
        if (idx < n) off[idx] = tbase + loc[i];
    }
    if (t == 255) bsum[blockIdx.x] = sm[255];
}

__global__ __launch_bounds__(256) void scan2(int* __restrict__ bsum, int nb) {
    __shared__ int sm[256];
    int t = threadIdx.x;
    int v = (t < nb) ? bsum[t] : 0;
    sm[t] = v;
    __syncthreads();
    for (int d = 1; d < 256; d <<= 1) {
        int u = (t >= d) ? sm[t - d] : 0;
        __syncthreads();
        sm[t] += u;
        __syncthreads();
    }
    if (t < nb) bsum[t] = sm[t] - v;
}

__global__ void scan3(int* __restrict__ off, int* __restrict__ cur,
                      const int* __restrict__ bsum, int n) {
    int i = blockIdx.x * blockDim.x + threadIdx.x;
    if (i < n) {
        int v = off[i] + bsum[i >> 11];
        off[i] = v;
        cur[i] = v;
    }
    if (i == 0) off[n] = N_EDGE;
}

__global__ void fill_kernel(const int* __restrict__ ridx, const int* __restrict__ cidx,
                            int* __restrict__ cur_ret, int* __restrict__ cur_orig,
                            int* __restrict__ el1, int* __restrict__ el2) {
    int e = blockIdx.x * blockDim.x + threadIdx.x;
    if (e < N_EDGE) {
        int r = ridx[e], c = cidx[e];
        int p1 = atomicAdd(&cur_ret[r], 1);  el1[p1] = c;
        int p2 = atomicAdd(&cur_orig[c], 1); el2[p2] = r;
    }
}

// ---------------- MFMA GEMM: out[M x BN] = A[M x 128] @ W[128 x BN], epilogues ----------------
// EPI 0: store bf16 plain
// EPI 1: store bf16 of relu(acc * inv_d(deg[row]) + bias[col])
// EPI 2: store f32  of acc + bias[col]
template<int BN, bool ABF16, int EPI>
__global__ __launch_bounds__(256) void gemm_k(
    const void* __restrict__ Asrc, const ushort* __restrict__ WT,
    const int* __restrict__ deg, const float* __restrict__ bias,
    void* __restrict__ outp, int M)
{
    __shared__ ushort Alds[64 * 128];
    __shared__ ushort Wlds[BN * 128];
    const int t = threadIdx.x;
    const int i0 = blockIdx.x * 64;

    // stage W^T (bf16, [n][k]) with XOR swizzle
    #pragma unroll
    for (int it = 0; it < BN / 16; ++it) {
        int idx = t + 256 * it;          // 16B unit
        int n = idx >> 4, u = idx & 15;
        int off = n * 256 + u * 16; off ^= (off >> 4) & 0x70;
        *(bf16x8*)&Wlds[off >> 1] = *(const bf16x8*)&WT[idx * 8];
    }
    // stage A rows (convert f32 -> bf16 if needed) with same swizzle
    if constexpr (ABF16) {
        const ushort* A = (const ushort*)Asrc;
        #pragma unroll
        for (int it = 0; it < 4; ++it) {
            int idx = t + 256 * it;
            int row = idx >> 4, u = idx & 15;
            int gr = min(i0 + row, M - 1);
            bf16x8 v = *(const bf16x8*)&A[(size_t)gr * 128 + u * 8];
            int off = row * 256 + u * 16; off ^= (off >> 4) & 0x70;
            *(bf16x8*)&Alds[off >> 1] = v;
        }
    } else {
        const float4* A = (const float4*)Asrc;
        #pragma unroll
        for (int it = 0; it < 8; ++it) {
            int row = (t >> 5) + 8 * it;
            int q = t & 31;
            int gr = min(i0 + row, M - 1);
            float4 v = A[(size_t)gr * 32 + q];
            ushort4 b; b.x = f2bf(v.x); b.y = f2bf(v.y); b.z = f2bf(v.z); b.w = f2bf(v.w);
            int off = row * 256 + q * 8; off ^= (off >> 4) & 0x70;
            *(ushort4*)&Alds[off >> 1] = b;
        }
    }
    __syncthreads();

    const int w = t >> 6, l = t & 63;
    const int r16 = l & 15, kg = l >> 4;
    const int arow = 16 * w + r16;

    bf16x8 a[4];
    #pragma unroll
    for (int ks = 0; ks < 4; ++ks) {
        int off = arow * 256 + kg * 16 + ks * 64; off ^= (off >> 4) & 0x70;
        a[ks] = *(const bf16x8*)&Alds[off >> 1];
    }
    f32x4 acc[BN / 16];
    #pragma unroll
    for (int cf = 0; cf < BN / 16; ++cf) acc[cf] = (f32x4){0.f, 0.f, 0.f, 0.f};
    #pragma unroll
    for (int cf = 0; cf < BN / 16; ++cf) {
        int n = cf * 16 + r16;
        #pragma unroll
        for (int ks = 0; ks < 4; ++ks) {
            int off = n * 256 + kg * 16 + ks * 64; off ^= (off >> 4) & 0x70;
            bf16x8 b = *(const bf16x8*)&Wlds[off >> 1];
            acc[cf] = __builtin_amdgcn_mfma_f32_16x16x32_bf16(a[ks], b, acc[cf], 0, 0, 0);
        }
    }

    #pragma unroll
    for (int r = 0; r < 4; ++r) {
        int gr = i0 + 16 * w + 4 * kg + r;
        if (gr >= M) continue;
        float di = 0.f;
        if constexpr (EPI == 1) {
            int dg = deg[gr];
            di = dg > 0 ? rsqrtf((float)dg) : 0.f;
        }
        #pragma unroll
        for (int cf = 0; cf < BN / 16; ++cf) {
            int col = cf * 16 + r16;
            float v = acc[cf][r];
            if constexpr (EPI == 0) {
                ((ushort*)outp)[(size_t)gr * BN + col] = f2bf(v);
            } else if constexpr (EPI == 1) {
                v = fmaxf(v * di + bias[col], 0.f);
                ((ushort*)outp)[(size_t)gr * BN + col] = f2bf(v);
            } else {
                ((float*)outp)[(size_t)gr * BN + col] = v + bias[col];
            }
        }
    }
}

// ---------------- gather + SAGE epilogue: r1s = bf16(relu(mean + xr + bl) * inv_s) ----------------
__global__ void gather_sage(const ushort* __restrict__ ho, const ushort* __restrict__ xr,
                            const int* __restrict__ off, const int* __restrict__ slist,
                            const float* __restrict__ bl, ushort* __restrict__ r1s) {
    int gt = blockIdx.x * 256 + threadIdx.x;
    int node = gt >> 4;
    if (node >= N_RET) return;
    int o8 = gt & 15;                     // owns 8 contiguous cols
    int s = off[node], e = off[node + 1];
    float acc[8] = {0.f, 0.f, 0.f, 0.f, 0.f, 0.f, 0.f, 0.f};
    for (int i = s; i < e; ++i) {
        int sn = slist[i];
        bf16x8 v = *(const bf16x8*)&ho[(size_t)sn * 128 + o8 * 8];
        #pragma unroll
        for (int j = 0; j < 8; ++j) acc[j] += bf2f((ushort)v[j]);
    }
    int deg = e - s;
    float rinv = 1.0f / fmaxf((float)deg, 1.0f);
    float sinv = deg > 0 ? rsqrtf((float)deg) : 0.f;
    bf16x8 xv = *(const bf16x8*)&xr[(size_t)node * 128 + o8 * 8];
    bf16x8 ov;
    #pragma unroll
    for (int j = 0; j < 8; ++j) {
        float v = fmaxf(acc[j] * rinv + bf2f((ushort)xv[j]) + bl[o8 * 8 + j], 0.f) * sinv;
        ov[j] = (short)f2bf(v);
    }
    *(bf16x8*)&r1s[(size_t)node * 128 + o8 * 8] = ov;
}

// ---------------- gather sum: g = bf16(sum of r1s rows) ----------------
__global__ void gather_sum(const ushort* __restrict__ src,
                           const int* __restrict__ off, const int* __restrict__ slist,
                           ushort* __restrict__ dst) {
    int gt = blockIdx.x * 256 + threadIdx.x;
    int node = gt >> 4;
    if (node >= N_ORIG) return;
    int o8 = gt & 15;
    int s = off[node], e = off[node + 1];
    float acc[8] = {0.f, 0.f, 0.f, 0.f, 0.f, 0.f, 0.f, 0.f};
    for (int i = s; i < e; ++i) {
        int sn = slist[i];
        bf16x8 v = *(const bf16x8*)&src[(size_t)sn * 128 + o8 * 8];
        #pragma unroll
        for (int j = 0; j < 8; ++j) acc[j] += bf2f((ushort)v[j]);
    }
    bf16x8 ov;
    #pragma unroll
    for (int j = 0; j < 8; ++j) ov[j] = (short)f2bf(acc[j]);
    *(bf16x8*)&dst[(size_t)node * 128 + o8 * 8] = ov;
}

extern "C" void kernel_launch(void* const* d_in, const int* in_sizes, int n_in,
                              void* d_out, int out_size, void* d_ws, size_t ws_size,
                              hipStream_t stream) {
    const float* x_ret    = (const float*)d_in[0];
    const float* x_orig   = (const float*)d_in[1];
    const int*   ret_idx  = (const int*)d_in[2];
    const int*   orig_idx = (const int*)d_in[3];
    const float* Wl1  = (const float*)d_in[6];
    const float* bl1  = (const float*)d_in[7];
    const float* Wr1  = (const float*)d_in[8];
    const float* Wg2  = (const float*)d_in[9];
    const float* bg2  = (const float*)d_in[10];
    const float* Wout = (const float*)d_in[14];
    const float* bout = (const float*)d_in[15];
    float* out = (float*)d_out;

    // workspace layout (16B-aligned regions first)
    ushort* hoB  = (ushort*)d_ws;                       // 100k*128 bf16 (h_o, later g)
    ushort* xrB  = hoB + (size_t)N_ORIG * 128;          // 200k*128 bf16 (xr, later t)
    ushort* r1sB = xrB + (size_t)N_RET * 128;           // 200k*128 bf16
    ushort* wtl1 = r1sB + (size_t)N_RET * 128;          // 16384
    ushort* wtr1 = wtl1 + 16384;                        // 16384
    ushort* wtg2 = wtr1 + 16384;                        // 16384
    ushort* wto  = wtg2 + 16384;                        // 8192
    int* cnt_ret  = (int*)(wto + 8192);                 // N_RET
    int* cnt_orig = cnt_ret + N_RET;                    // N_ORIG
    int* off_ret  = cnt_orig + N_ORIG;                  // N_RET+1
    int* off_orig = off_ret + N_RET + 1;                // N_ORIG+1
    int* cur_ret  = off_orig + N_ORIG + 1;              // N_RET
    int* cur_orig = cur_ret + N_RET;                    // N_ORIG
    int* bsum1    = cur_orig + N_ORIG;                  // 256
    int* bsum2    = bsum1 + 256;                        // 256
    int* el1      = bsum2 + 256;                        // N_EDGE
    int* el2      = el1 + N_EDGE;                       // N_EDGE

    // weights -> transposed bf16
    wt_kernel<<<64, 256, 0, stream>>>(Wl1,  wtl1, 16384, 7);
    wt_kernel<<<64, 256, 0, stream>>>(Wr1,  wtr1, 16384, 7);
    wt_kernel<<<64, 256, 0, stream>>>(Wg2,  wtg2, 16384, 7);
    wt_kernel<<<32, 256, 0, stream>>>(Wout, wto,  8192,  6);

    // CSR build
    hipMemsetAsync(cnt_ret, 0, (size_t)(N_RET + N_ORIG) * sizeof(int), stream);
    count_kernel<<<(N_EDGE + 255) / 256, 256, 0, stream>>>(ret_idx, orig_idx, cnt_ret, cnt_orig);
    const int nb_ret  = (N_RET  + SCAN_ELEMS - 1) / SCAN_ELEMS;
    const int nb_orig = (N_ORIG + SCAN_ELEMS - 1) / SCAN_ELEMS;
    scan1<<<nb_ret,  256, 0, stream>>>(cnt_ret,  off_ret,  bsum1, N_RET);
    scan1<<<nb_orig, 256, 0, stream>>>(cnt_orig, off_orig, bsum2, N_ORIG);
    scan2<<<1, 256, 0, stream>>>(bsum1, nb_ret);
    scan2<<<1, 256, 0, stream>>>(bsum2, nb_orig);
    scan3<<<(N_RET  + 255) / 256, 256, 0, stream>>>(off_ret,  cur_ret,  bsum1, N_RET);
    scan3<<<(N_ORIG + 255) / 256, 256, 0, stream>>>(off_orig, cur_orig, bsum2, N_ORIG);
    fill_kernel<<<(N_EDGE + 255) / 256, 256, 0, stream>>>(ret_idx, orig_idx,
                                                          cur_ret, cur_orig, el1, el2);

    // h_o = bf16(x_orig @ Wl1)            [100k x 128]
    gemm_k<128, false, 0><<<(N_ORIG + 63) / 64, 256, 0, stream>>>(
        x_orig, wtl1, nullptr, nullptr, hoB, N_ORIG);
    // xr = bf16(x_ret @ Wr1)              [200k x 128]
    gemm_k<128, false, 0><<<(N_RET + 63) / 64, 256, 0, stream>>>(
        x_ret, wtr1, nullptr, nullptr, xrB, N_RET);

    // r1s = bf16(relu(mean_agg(h_o) + xr + bl1) * inv_s)   [200k x 128]
    gather_sage<<<(N_RET * 16) / 256, 256, 0, stream>>>(hoB, xrB, off_ret, el1, bl1, r1sB);

    // g = bf16(segment_sum(r1s))          [100k x 128]  (reuses hoB)
    gather_sum<<<(N_ORIG * 16) / 256, 256, 0, stream>>>(r1sB, off_orig, el2, hoB);

    // t = bf16(relu((g @ Wg2) * inv_d + bg2))   [100k x 128]  (reuses xrB)
    gemm_k<128, true, 1><<<(N_ORIG + 63) / 64, 256, 0, stream>>>(
        hoB, wtg2, cnt_orig, bg2, xrB, N_ORIG);

    // out = (t @ Wout) + bout             [100k x 64] f32
    gemm_k<64, true, 2><<<(N_ORIG + 63) / 64, 256, 0, stream>>>(
        xrB, wto, nullptr, bout, out, N_ORIG);
}

// Round 4
// 333.554 us; speedup vs baseline: 9.2479x; 1.1530x over previous
//
#include <hip/hip_runtime.h>

#define N_RET  200000
#define N_ORIG 100000
#define N_EDGE 800000
#define SCAN_ELEMS 2048
#define NB_RET  ((N_RET  + 511) >> 9)   // 391 buckets of 512 nodes
#define NB_ORIG ((N_ORIG + 511) >> 9)   // 196

typedef __attribute__((ext_vector_type(8))) short bf16x8;   // 8 bf16 (4 VGPRs)
typedef __attribute__((ext_vector_type(4))) float f32x4;    // MFMA C/D

__device__ __forceinline__ ushort f2bf(float f) {
    union { float f; unsigned u; } v; v.f = f;
    unsigned r = v.u + 0x7FFFu + ((v.u >> 16) & 1u);   // RNE
    return (ushort)(r >> 16);
}
__device__ __forceinline__ float bf2f(ushort u) {
    union { unsigned u; float f; } v; v.u = ((unsigned)u) << 16;
    return v.f;
}

// ---------------- weight transpose + bf16 convert: WT[n][k] = bf16(W[k][n]) ----------------
__global__ void wt_kernel(const float* __restrict__ W, ushort* __restrict__ WT,
                          int total, int nshift) {
    int i = blockIdx.x * 256 + threadIdx.x;
    if (i >= total) return;
    int N = 1 << nshift;
    int k = i >> nshift, n = i & (N - 1);
    int K = total >> nshift;
    WT[n * K + k] = f2bf(W[i]);
}

// ---------------- CSR build ----------------
__global__ void count_kernel(const int* __restrict__ ridx, const int* __restrict__ cidx,
                             int* __restrict__ cret, int* __restrict__ corig) {
    int e = blockIdx.x * blockDim.x + threadIdx.x;
    if (e < N_EDGE) {
        atomicAdd(&cret[ridx[e]], 1);
        atomicAdd(&corig[cidx[e]], 1);
    }
}

__global__ __launch_bounds__(256) void scan1(const int* __restrict__ cnt,
                                             int* __restrict__ off,
                                             int* __restrict__ bsum, int n) {
    __shared__ int sm[256];
    int t = threadIdx.x;
    int base = blockIdx.x * SCAN_ELEMS;
    int loc[8];
    int s = 0;
    #pragma unroll
    for (int i = 0; i < 8; ++i) {
        int idx = base + t * 8 + i;
        int v = (idx < n) ? cnt[idx] : 0;
        loc[i] = s;
        s += v;
    }
    sm[t] = s;
    __syncthreads();
    for (int d = 1; d < 256; d <<= 1) {
        int v = (t >= d) ? sm[t - d] : 0;
        __syncthreads();
        sm[t] += v;
        __syncthreads();
    }
    int tbase = (t > 0) ? sm[t - 1] : 0;
    #pragma unroll
    for (int i = 0; i < 8; ++i) {
        int idx = base + t * 8 + i;
        if (idx < n) off[idx] = tbase + loc[i];
    }
    if (t == 255) bsum[blockIdx.x] = sm[255];
}

__global__ __launch_bounds__(256) void scan2(int* __restrict__ bsum, int nb) {
    __shared__ int sm[256];
    int t = threadIdx.x;
    int v = (t < nb) ? bsum[t] : 0;
    sm[t] = v;
    __syncthreads();
    for (int d = 1; d < 256; d <<= 1) {
        int u = (t >= d) ? sm[t - d] : 0;
        __syncthreads();
        sm[t] += u;
        __syncthreads();
    }
    if (t < nb) bsum[t] = sm[t] - v;
}

__global__ void scan3(int* __restrict__ off, const int* __restrict__ bsum, int n) {
    int i = blockIdx.x * blockDim.x + threadIdx.x;
    if (i < n) off[i] += bsum[i >> 11];
    if (i == 0) off[n] = N_EDGE;
}

// ---------------- bucket cursor init: bcur[b] = off[b<<9] ----------------
__global__ void initb_kernel(const int* __restrict__ off_ret, const int* __restrict__ off_orig,
                             int* __restrict__ bcur1, int* __restrict__ bcur2) {
    int t = threadIdx.x;
    if (t < NB_RET)  bcur1[t] = off_ret[t << 9];
    if (t < NB_ORIG) bcur2[t] = off_orig[t << 9];
}

// ---------------- pass A: bin edges by dst bucket; record (local_dst<<18)|src ----------------
__global__ __launch_bounds__(256) void bin_kernel(const int* __restrict__ dst,
                                                  const int* __restrict__ src,
                                                  int* __restrict__ bcur,
                                                  int* __restrict__ binned,
                                                  int nbuckets) {
    __shared__ int hist[512], base[512], lcur[512];
    const int t = threadIdx.x;
    const int c0 = blockIdx.x * 8192;
    for (int i = t; i < 512; i += 256) { hist[i] = 0; lcur[i] = 0; }
    __syncthreads();
    for (int i = t; i < 8192; i += 256) {
        int e = c0 + i;
        if (e < N_EDGE) atomicAdd(&hist[dst[e] >> 9], 1);
    }
    __syncthreads();
    for (int b = t; b < nbuckets; b += 256)
        base[b] = hist[b] > 0 ? atomicAdd(&bcur[b], hist[b]) : 0;
    __syncthreads();
    for (int i = t; i < 8192; i += 256) {
        int e = c0 + i;
        if (e < N_EDGE) {
            int d = dst[e];
            int b = d >> 9;
            int r = atomicAdd(&lcur[b], 1);
            binned[base[b] + r] = ((d & 511) << 18) | src[e];
        }
    }
}

// ---------------- pass B: per-bucket CSR fill with LDS cursors ----------------
__global__ __launch_bounds__(256) void fill2_kernel(const int* __restrict__ binned,
                                                    const int* __restrict__ off,
                                                    int* __restrict__ el, int nnodes) {
    __shared__ int cur[512];
    __shared__ int se[2];
    const int t = threadIdx.x;
    const int base = blockIdx.x << 9;
    const int nvalid = min(512, nnodes - base);
    for (int i = t; i < nvalid; i += 256) cur[i] = off[base + i];
    if (t == 0) { se[0] = off[base]; se[1] = off[base + nvalid]; }
    __syncthreads();
    for (int i = se[0] + t; i < se[1]; i += 256) {
        int v = binned[i];
        int p = atomicAdd(&cur[v >> 18], 1);
        el[p] = v & 0x3FFFF;
    }
}

// ---------------- MFMA GEMM: out[M x BN] = A[M x 128] @ W[128 x BN], epilogues ----------------
// EPI 0: store bf16 plain
// EPI 1: store bf16 of relu(acc * inv_d(deg[row]) + bias[col])
// EPI 2: store f32  of acc + bias[col]
template<int BN, bool ABF16, int EPI>
__global__ __launch_bounds__(256) void gemm_k(
    const void* __restrict__ Asrc, const ushort* __restrict__ WT,
    const int* __restrict__ deg, const float* __restrict__ bias,
    void* __restrict__ outp, int M)
{
    __shared__ ushort Alds[64 * 128];
    __shared__ ushort Wlds[BN * 128];
    const int t = threadIdx.x;
    const int i0 = blockIdx.x * 64;

    #pragma unroll
    for (int it = 0; it < BN / 16; ++it) {
        int idx = t + 256 * it;
        int n = idx >> 4, u = idx & 15;
        int off = n * 256 + u * 16; off ^= (off >> 4) & 0x70;
        *(bf16x8*)&Wlds[off >> 1] = *(const bf16x8*)&WT[idx * 8];
    }
    if constexpr (ABF16) {
        const ushort* A = (const ushort*)Asrc;
        #pragma unroll
        for (int it = 0; it < 4; ++it) {
            int idx = t + 256 * it;
            int row = idx >> 4, u = idx & 15;
            int gr = min(i0 + row, M - 1);
            bf16x8 v = *(const bf16x8*)&A[(size_t)gr * 128 + u * 8];
            int off = row * 256 + u * 16; off ^= (off >> 4) & 0x70;
            *(bf16x8*)&Alds[off >> 1] = v;
        }
    } else {
        const float4* A = (const float4*)Asrc;
        #pragma unroll
        for (int it = 0; it < 8; ++it) {
            int row = (t >> 5) + 8 * it;
            int q = t & 31;
            int gr = min(i0 + row, M - 1);
            float4 v = A[(size_t)gr * 32 + q];
            ushort4 b; b.x = f2bf(v.x); b.y = f2bf(v.y); b.z = f2bf(v.z); b.w = f2bf(v.w);
            int off = row * 256 + q * 8; off ^= (off >> 4) & 0x70;
            *(ushort4*)&Alds[off >> 1] = b;
        }
    }
    __syncthreads();

    const int w = t >> 6, l = t & 63;
    const int r16 = l & 15, kg = l >> 4;
    const int arow = 16 * w + r16;

    bf16x8 a[4];
    #pragma unroll
    for (int ks = 0; ks < 4; ++ks) {
        int off = arow * 256 + kg * 16 + ks * 64; off ^= (off >> 4) & 0x70;
        a[ks] = *(const bf16x8*)&Alds[off >> 1];
    }
    f32x4 acc[BN / 16];
    #pragma unroll
    for (int cf = 0; cf < BN / 16; ++cf) acc[cf] = (f32x4){0.f, 0.f, 0.f, 0.f};
    #pragma unroll
    for (int cf = 0; cf < BN / 16; ++cf) {
        int n = cf * 16 + r16;
        #pragma unroll
        for (int ks = 0; ks < 4; ++ks) {
            int off = n * 256 + kg * 16 + ks * 64; off ^= (off >> 4) & 0x70;
            bf16x8 b = *(const bf16x8*)&Wlds[off >> 1];
            acc[cf] = __builtin_amdgcn_mfma_f32_16x16x32_bf16(a[ks], b, acc[cf], 0, 0, 0);
        }
    }

    #pragma unroll
    for (int r = 0; r < 4; ++r) {
        int gr = i0 + 16 * w + 4 * kg + r;
        if (gr >= M) continue;
        float di = 0.f;
        if constexpr (EPI == 1) {
            int dg = deg[gr];
            di = dg > 0 ? rsqrtf((float)dg) : 0.f;
        }
        #pragma unroll
        for (int cf = 0; cf < BN / 16; ++cf) {
            int col = cf * 16 + r16;
            float v = acc[cf][r];
            if constexpr (EPI == 0) {
                ((ushort*)outp)[(size_t)gr * BN + col] = f2bf(v);
            } else if constexpr (EPI == 1) {
                v = fmaxf(v * di + bias[col], 0.f);
                ((ushort*)outp)[(size_t)gr * BN + col] = f2bf(v);
            } else {
                ((float*)outp)[(size_t)gr * BN + col] = v + bias[col];
            }
        }
    }
}

// ---------------- gather + SAGE epilogue: r1s = bf16(relu(mean + xr + bl) * inv_s) ----------------
__global__ void gather_sage(const ushort* __restrict__ ho, const ushort* __restrict__ xr,
                            const int* __restrict__ off, const int* __restrict__ slist,
                            const float* __restrict__ bl, ushort* __restrict__ r1s) {
    int gt = blockIdx.x * 256 + threadIdx.x;
    int node = gt >> 4;
    if (node >= N_RET) return;
    int o8 = gt & 15;
    int s = off[node], e = off[node + 1];
    float acc[8] = {0.f, 0.f, 0.f, 0.f, 0.f, 0.f, 0.f, 0.f};
    for (int i = s; i < e; ++i) {
        int sn = slist[i];
        bf16x8 v = *(const bf16x8*)&ho[(size_t)sn * 128 + o8 * 8];
        #pragma unroll
        for (int j = 0; j < 8; ++j) acc[j] += bf2f((ushort)v[j]);
    }
    int deg = e - s;
    float rinv = 1.0f / fmaxf((float)deg, 1.0f);
    float sinv = deg > 0 ? rsqrtf((float)deg) : 0.f;
    bf16x8 xv = *(const bf16x8*)&xr[(size_t)node * 128 + o8 * 8];
    bf16x8 ov;
    #pragma unroll
    for (int j = 0; j < 8; ++j) {
        float v = fmaxf(acc[j] * rinv + bf2f((ushort)xv[j]) + bl[o8 * 8 + j], 0.f) * sinv;
        ov[j] = (short)f2bf(v);
    }
    *(bf16x8*)&r1s[(size_t)node * 128 + o8 * 8] = ov;
}

// ---------------- gather sum: g = bf16(sum of r1s rows) ----------------
__global__ void gather_sum(const ushort* __restrict__ src,
                           const int* __restrict__ off, const int* __restrict__ slist,
                           ushort* __restrict__ dst) {
    int gt = blockIdx.x * 256 + threadIdx.x;
    int node = gt >> 4;
    if (node >= N_ORIG) return;
    int o8 = gt & 15;
    int s = off[node], e = off[node + 1];
    float acc[8] = {0.f, 0.f, 0.f, 0.f, 0.f, 0.f, 0.f, 0.f};
    for (int i = s; i < e; ++i) {
        int sn = slist[i];
        bf16x8 v = *(const bf16x8*)&src[(size_t)sn * 128 + o8 * 8];
        #pragma unroll
        for (int j = 0; j < 8; ++j) acc[j] += bf2f((ushort)v[j]);
    }
    bf16x8 ov;
    #pragma unroll
    for (int j = 0; j < 8; ++j) ov[j] = (short)f2bf(acc[j]);
    *(bf16x8*)&dst[(size_t)node * 128 + o8 * 8] = ov;
}

extern "C" void kernel_launch(void* const* d_in, const int* in_sizes, int n_in,
                              void* d_out, int out_size, void* d_ws, size_t ws_size,
                              hipStream_t stream) {
    const float* x_ret    = (const float*)d_in[0];
    const float* x_orig   = (const float*)d_in[1];
    const int*   ret_idx  = (const int*)d_in[2];
    const int*   orig_idx = (const int*)d_in[3];
    const float* Wl1  = (const float*)d_in[6];
    const float* bl1  = (const float*)d_in[7];
    const float* Wr1  = (const float*)d_in[8];
    const float* Wg2  = (const float*)d_in[9];
    const float* bg2  = (const float*)d_in[10];
    const float* Wout = (const float*)d_in[14];
    const float* bout = (const float*)d_in[15];
    float* out = (float*)d_out;

    // workspace layout (16B-aligned regions first)
    ushort* hoB  = (ushort*)d_ws;                       // 100k*128 bf16 (h_o, later g)
    ushort* xrB  = hoB + (size_t)N_ORIG * 128;          // 200k*128 bf16 (xr, later t)
    ushort* r1sB = xrB + (size_t)N_RET * 128;           // 200k*128 bf16
    ushort* wtl1 = r1sB + (size_t)N_RET * 128;          // 16384
    ushort* wtr1 = wtl1 + 16384;                        // 16384
    ushort* wtg2 = wtr1 + 16384;                        // 16384
    ushort* wto  = wtg2 + 16384;                        // 8192
    int* cnt_ret  = (int*)(wto + 8192);                 // N_RET
    int* cnt_orig = cnt_ret + N_RET;                    // N_ORIG
    int* off_ret  = cnt_orig + N_ORIG;                  // N_RET+1
    int* off_orig = off_ret + N_RET + 1;                // N_ORIG+1
    int* bcur1    = off_orig + N_ORIG + 1;              // 512
    int* bcur2    = bcur1 + 512;                        // 512
    int* bsum1    = bcur2 + 512;                        // 256
    int* bsum2    = bsum1 + 256;                        // 256
    int* el1      = bsum2 + 256;                        // N_EDGE (src=orig, grouped by ret)
    int* el2      = el1 + N_EDGE;                       // N_EDGE (src=ret, grouped by orig)
    int* binned1  = el2 + N_EDGE;                       // N_EDGE packed
    int* binned2  = binned1 + N_EDGE;                   // N_EDGE packed

    // weights -> transposed bf16
    wt_kernel<<<64, 256, 0, stream>>>(Wl1,  wtl1, 16384, 7);
    wt_kernel<<<64, 256, 0, stream>>>(Wr1,  wtr1, 16384, 7);
    wt_kernel<<<64, 256, 0, stream>>>(Wg2,  wtg2, 16384, 7);
    wt_kernel<<<32, 256, 0, stream>>>(Wout, wto,  8192,  6);

    // CSR build
    hipMemsetAsync(cnt_ret, 0, (size_t)(N_RET + N_ORIG) * sizeof(int), stream);
    count_kernel<<<(N_EDGE + 255) / 256, 256, 0, stream>>>(ret_idx, orig_idx, cnt_ret, cnt_orig);
    const int nb_ret  = (N_RET  + SCAN_ELEMS - 1) / SCAN_ELEMS;
    const int nb_orig = (N_ORIG + SCAN_ELEMS - 1) / SCAN_ELEMS;
    scan1<<<nb_ret,  256, 0, stream>>>(cnt_ret,  off_ret,  bsum1, N_RET);
    scan1<<<nb_orig, 256, 0, stream>>>(cnt_orig, off_orig, bsum2, N_ORIG);
    scan2<<<1, 256, 0, stream>>>(bsum1, nb_ret);
    scan2<<<1, 256, 0, stream>>>(bsum2, nb_orig);
    scan3<<<(N_RET  + 255) / 256, 256, 0, stream>>>(off_ret,  bsum1, N_RET);
    scan3<<<(N_ORIG + 255) / 256, 256, 0, stream>>>(off_orig, bsum2, N_ORIG);

    // two-level binned fill (replaces direct scattered fill)
    initb_kernel<<<1, 512, 0, stream>>>(off_ret, off_orig, bcur1, bcur2);
    const int nbin_blocks = (N_EDGE + 8191) / 8192;
    bin_kernel<<<nbin_blocks, 256, 0, stream>>>(ret_idx, orig_idx, bcur1, binned1, NB_RET);
    bin_kernel<<<nbin_blocks, 256, 0, stream>>>(orig_idx, ret_idx, bcur2, binned2, NB_ORIG);
    fill2_kernel<<<NB_RET,  256, 0, stream>>>(binned1, off_ret,  el1, N_RET);
    fill2_kernel<<<NB_ORIG, 256, 0, stream>>>(binned2, off_orig, el2, N_ORIG);

    // h_o = bf16(x_orig @ Wl1)            [100k x 128]
    gemm_k<128, false, 0><<<(N_ORIG + 63) / 64, 256, 0, stream>>>(
        x_orig, wtl1, nullptr, nullptr, hoB, N_ORIG);
    // xr = bf16(x_ret @ Wr1)              [200k x 128]
    gemm_k<128, false, 0><<<(N_RET + 63) / 64, 256, 0, stream>>>(
        x_ret, wtr1, nullptr, nullptr, xrB, N_RET);

    // r1s = bf16(relu(mean_agg(h_o) + xr + bl1) * inv_s)   [200k x 128]
    gather_sage<<<(N_RET * 16) / 256, 256, 0, stream>>>(hoB, xrB, off_ret, el1, bl1, r1sB);

    // g = bf16(segment_sum(r1s))          [100k x 128]  (reuses hoB)
    gather_sum<<<(N_ORIG * 16) / 256, 256, 0, stream>>>(r1sB, off_orig, el2, hoB);

    // t = bf16(relu((g @ Wg2) * inv_d + bg2))   [100k x 128]  (reuses xrB)
    gemm_k<128, true, 1><<<(N_ORIG + 63) / 64, 256, 0, stream>>>(
        hoB, wtg2, cnt_orig, bg2, xrB, N_ORIG);

    // out = (t @ Wout) + bout             [100k x 64] f32
    gemm_k<64, true, 2><<<(N_ORIG + 63) / 64, 256, 0, stream>>>(
        xrB, wto, nullptr, bout, out, N_ORIG);
}

// Round 5
// 281.282 us; speedup vs baseline: 10.9665x; 1.1858x over previous
//
#include <hip/hip_runtime.h>

#define N_RET  200000
#define N_ORIG 100000
#define N_EDGE 800000
#define NB_RET  ((N_RET  + 511) >> 9)   // 391 buckets of 512 nodes
#define NB_ORIG ((N_ORIG + 511) >> 9)   // 196

typedef __attribute__((ext_vector_type(8))) short bf16x8;   // 8 bf16 (4 VGPRs)
typedef __attribute__((ext_vector_type(4))) float f32x4;    // MFMA C/D

__device__ __forceinline__ ushort f2bf(float f) {
    union { float f; unsigned u; } v; v.f = f;
    unsigned r = v.u + 0x7FFFu + ((v.u >> 16) & 1u);   // RNE
    return (ushort)(r >> 16);
}
__device__ __forceinline__ float bf2f(ushort u) {
    union { unsigned u; float f; } v; v.u = ((unsigned)u) << 16;
    return v.f;
}

// ---------------- weight transpose + bf16 convert: WT[n][k] = bf16(W[k][n]) ----------------
__global__ void wt_kernel(const float* __restrict__ W, ushort* __restrict__ WT,
                          int total, int nshift) {
    int i = blockIdx.x * 256 + threadIdx.x;
    if (i >= total) return;
    int N = 1 << nshift;
    int k = i >> nshift, n = i & (N - 1);
    int K = total >> nshift;
    WT[n * K + k] = f2bf(W[i]);
}

// ---------------- bucket-level histogram (both directions in one pass) ----------------
__global__ __launch_bounds__(256) void bucket_count(const int* __restrict__ ridx,
                                                    const int* __restrict__ cidx,
                                                    int* __restrict__ bcnt1,
                                                    int* __restrict__ bcnt2) {
    __shared__ int h1[512], h2[512];
    const int t = threadIdx.x;
    const int c0 = blockIdx.x * 8192;
    for (int i = t; i < 512; i += 256) { h1[i] = 0; h2[i] = 0; }
    __syncthreads();
    for (int i = t; i < 8192; i += 256) {
        int e = c0 + i;
        if (e < N_EDGE) {
            atomicAdd(&h1[ridx[e] >> 9], 1);
            atomicAdd(&h2[cidx[e] >> 9], 1);
        }
    }
    __syncthreads();
    for (int b = t; b < NB_RET; b += 256)
        if (h1[b]) atomicAdd(&bcnt1[b], h1[b]);
    for (int b = t; b < NB_ORIG; b += 256)
        if (h2[b]) atomicAdd(&bcnt2[b], h2[b]);
}

// ---------------- single-block scan of bucket counts -> bucket offsets + cursors ----------------
__global__ __launch_bounds__(256) void scan_buckets(const int* __restrict__ bcnt1,
                                                    int* __restrict__ boff1, int* __restrict__ bcur1,
                                                    const int* __restrict__ bcnt2,
                                                    int* __restrict__ boff2, int* __restrict__ bcur2,
                                                    int* __restrict__ off_ret,
                                                    int* __restrict__ off_orig) {
    __shared__ int sm[256];
    const int t = threadIdx.x;
    {
        int a0 = (2 * t     < NB_RET) ? bcnt1[2 * t]     : 0;
        int a1 = (2 * t + 1 < NB_RET) ? bcnt1[2 * t + 1] : 0;
        sm[t] = a0 + a1;
        __syncthreads();
        for (int d = 1; d < 256; d <<= 1) {
            int v = (t >= d) ? sm[t - d] : 0;
            __syncthreads(); sm[t] += v; __syncthreads();
        }
        int tb = t ? sm[t - 1] : 0;
        if (2 * t < NB_RET)     { boff1[2 * t]     = tb;      bcur1[2 * t]     = tb; }
        if (2 * t + 1 < NB_RET) { boff1[2 * t + 1] = tb + a0; bcur1[2 * t + 1] = tb + a0; }
        if (t == 0) { boff1[NB_RET] = N_EDGE; off_ret[N_RET] = N_EDGE; }
        __syncthreads();
    }
    {
        int a0 = (2 * t     < NB_ORIG) ? bcnt2[2 * t]     : 0;
        int a1 = (2 * t + 1 < NB_ORIG) ? bcnt2[2 * t + 1] : 0;
        sm[t] = a0 + a1;
        __syncthreads();
        for (int d = 1; d < 256; d <<= 1) {
            int v = (t >= d) ? sm[t - d] : 0;
            __syncthreads(); sm[t] += v; __syncthreads();
        }
        int tb = t ? sm[t - 1] : 0;
        if (2 * t < NB_ORIG)     { boff2[2 * t]     = tb;      bcur2[2 * t]     = tb; }
        if (2 * t + 1 < NB_ORIG) { boff2[2 * t + 1] = tb + a0; bcur2[2 * t + 1] = tb + a0; }
        if (t == 0) { boff2[NB_ORIG] = N_EDGE; off_orig[N_ORIG] = N_EDGE; }
    }
}

// ---------------- pass A: bin edges by dst bucket; record (local_dst<<18)|src ----------------
__global__ __launch_bounds__(256) void bin_kernel(const int* __restrict__ dst,
                                                  const int* __restrict__ src,
                                                  int* __restrict__ bcur,
                                                  int* __restrict__ binned,
                                                  int nbuckets) {
    __shared__ int hist[512], base[512], lcur[512];
    const int t = threadIdx.x;
    const int c0 = blockIdx.x * 8192;
    for (int i = t; i < 512; i += 256) { hist[i] = 0; lcur[i] = 0; }
    __syncthreads();
    for (int i = t; i < 8192; i += 256) {
        int e = c0 + i;
        if (e < N_EDGE) atomicAdd(&hist[dst[e] >> 9], 1);
    }
    __syncthreads();
    for (int b = t; b < nbuckets; b += 256)
        base[b] = hist[b] > 0 ? atomicAdd(&bcur[b], hist[b]) : 0;
    __syncthreads();
    for (int i = t; i < 8192; i += 256) {
        int e = c0 + i;
        if (e < N_EDGE) {
            int d = dst[e];
            int b = d >> 9;
            int r = atomicAdd(&lcur[b], 1);
            binned[base[b] + r] = ((d & 511) << 18) | src[e];
        }
    }
}

// ---------------- pass B: per-bucket node-offset build + CSR fill ----------------
__global__ __launch_bounds__(256) void fill2_kernel(const int* __restrict__ binned,
                                                    const int* __restrict__ boff,
                                                    int* __restrict__ off,
                                                    int* __restrict__ el, int nnodes) {
    __shared__ int hist[512];     // node histogram, then reused as cursors
    __shared__ int sm[256];
    const int t = threadIdx.x;
    const int base = blockIdx.x << 9;
    const int nvalid = min(512, nnodes - base);
    const int s0 = boff[blockIdx.x], s1 = boff[blockIdx.x + 1];
    for (int i = t; i < 512; i += 256) hist[i] = 0;
    __syncthreads();
    for (int i = s0 + t; i < s1; i += 256)
        atomicAdd(&hist[binned[i] >> 18], 1);
    __syncthreads();
    int a0 = hist[2 * t], a1 = hist[2 * t + 1];
    sm[t] = a0 + a1;
    __syncthreads();
    for (int d = 1; d < 256; d <<= 1) {
        int v = (t >= d) ? sm[t - d] : 0;
        __syncthreads(); sm[t] += v; __syncthreads();
    }
    int tb = (t ? sm[t - 1] : 0) + s0;
    // node offsets + cursors
    if (2 * t < nvalid)     off[base + 2 * t]     = tb;
    if (2 * t + 1 < nvalid) off[base + 2 * t + 1] = tb + a0;
    hist[2 * t] = tb;
    hist[2 * t + 1] = tb + a0;
    __syncthreads();
    for (int i = s0 + t; i < s1; i += 256) {
        int v = binned[i];
        int p = atomicAdd(&hist[v >> 18], 1);
        el[p] = v & 0x3FFFF;
    }
}

// ---------------- MFMA GEMM: out[M x BN] = A[M x 128] @ W[128 x BN], epilogues ----------------
// EPI 0: store bf16 plain
// EPI 1: store bf16 of relu(acc * inv_d(off-diff) + bias[col])
// EPI 2: store f32  of acc + bias[col]
template<int BN, bool ABF16, int EPI>
__global__ __launch_bounds__(256) void gemm_k(
    const void* __restrict__ Asrc, const ushort* __restrict__ WT,
    const int* __restrict__ offd, const float* __restrict__ bias,
    void* __restrict__ outp, int M)
{
    __shared__ ushort Alds[64 * 128];
    __shared__ ushort Wlds[BN * 128];
    const int t = threadIdx.x;
    const int i0 = blockIdx.x * 64;

    #pragma unroll
    for (int it = 0; it < BN / 16; ++it) {
        int idx = t + 256 * it;
        int n = idx >> 4, u = idx & 15;
        int off = n * 256 + u * 16; off ^= (off >> 4) & 0x70;
        *(bf16x8*)&Wlds[off >> 1] = *(const bf16x8*)&WT[idx * 8];
    }
    if constexpr (ABF16) {
        const ushort* A = (const ushort*)Asrc;
        #pragma unroll
        for (int it = 0; it < 4; ++it) {
            int idx = t + 256 * it;
            int row = idx >> 4, u = idx & 15;
            int gr = min(i0 + row, M - 1);
            bf16x8 v = *(const bf16x8*)&A[(size_t)gr * 128 + u * 8];
            int off = row * 256 + u * 16; off ^= (off >> 4) & 0x70;
            *(bf16x8*)&Alds[off >> 1] = v;
        }
    } else {
        const float4* A = (const float4*)Asrc;
        #pragma unroll
        for (int it = 0; it < 8; ++it) {
            int row = (t >> 5) + 8 * it;
            int q = t & 31;
            int gr = min(i0 + row, M - 1);
            float4 v = A[(size_t)gr * 32 + q];
            ushort4 b; b.x = f2bf(v.x); b.y = f2bf(v.y); b.z = f2bf(v.z); b.w = f2bf(v.w);
            int off = row * 256 + q * 8; off ^= (off >> 4) & 0x70;
            *(ushort4*)&Alds[off >> 1] = b;
        }
    }
    __syncthreads();

    const int w = t >> 6, l = t & 63;
    const int r16 = l & 15, kg = l >> 4;
    const int arow = 16 * w + r16;

    bf16x8 a[4];
    #pragma unroll
    for (int ks = 0; ks < 4; ++ks) {
        int off = arow * 256 + kg * 16 + ks * 64; off ^= (off >> 4) & 0x70;
        a[ks] = *(const bf16x8*)&Alds[off >> 1];
    }
    f32x4 acc[BN / 16];
    #pragma unroll
    for (int cf = 0; cf < BN / 16; ++cf) acc[cf] = (f32x4){0.f, 0.f, 0.f, 0.f};
    #pragma unroll
    for (int cf = 0; cf < BN / 16; ++cf) {
        int n = cf * 16 + r16;
        #pragma unroll
        for (int ks = 0; ks < 4; ++ks) {
            int off = n * 256 + kg * 16 + ks * 64; off ^= (off >> 4) & 0x70;
            bf16x8 b = *(const bf16x8*)&Wlds[off >> 1];
            acc[cf] = __builtin_amdgcn_mfma_f32_16x16x32_bf16(a[ks], b, acc[cf], 0, 0, 0);
        }
    }

    #pragma unroll
    for (int r = 0; r < 4; ++r) {
        int gr = i0 + 16 * w + 4 * kg + r;
        if (gr >= M) continue;
        float di = 0.f;
        if constexpr (EPI == 1) {
            int dg = offd[gr + 1] - offd[gr];
            di = dg > 0 ? rsqrtf((float)dg) : 0.f;
        }
        #pragma unroll
        for (int cf = 0; cf < BN / 16; ++cf) {
            int col = cf * 16 + r16;
            float v = acc[cf][r];
            if constexpr (EPI == 0) {
                ((ushort*)outp)[(size_t)gr * BN + col] = f2bf(v);
            } else if constexpr (EPI == 1) {
                v = fmaxf(v * di + bias[col], 0.f);
                ((ushort*)outp)[(size_t)gr * BN + col] = f2bf(v);
            } else {
                ((float*)outp)[(size_t)gr * BN + col] = v + bias[col];
            }
        }
    }
}

// ---------------- gather + SAGE epilogue: r1s = bf16(relu(mean + xr + bl) * inv_s) ----------------
__global__ void gather_sage(const ushort* __restrict__ ho, const ushort* __restrict__ xr,
                            const int* __restrict__ off, const int* __restrict__ slist,
                            const float* __restrict__ bl, ushort* __restrict__ r1s) {
    int gt = blockIdx.x * 256 + threadIdx.x;
    int node = gt >> 4;
    if (node >= N_RET) return;
    int o8 = gt & 15;
    int s = off[node], e = off[node + 1];
    float acc[8] = {0.f, 0.f, 0.f, 0.f, 0.f, 0.f, 0.f, 0.f};
    for (int i = s; i < e; ++i) {
        int sn = slist[i];
        bf16x8 v = *(const bf16x8*)&ho[(size_t)sn * 128 + o8 * 8];
        #pragma unroll
        for (int j = 0; j < 8; ++j) acc[j] += bf2f((ushort)v[j]);
    }
    int deg = e - s;
    float rinv = 1.0f / fmaxf((float)deg, 1.0f);
    float sinv = deg > 0 ? rsqrtf((float)deg) : 0.f;
    bf16x8 xv = *(const bf16x8*)&xr[(size_t)node * 128 + o8 * 8];
    bf16x8 ov;
    #pragma unroll
    for (int j = 0; j < 8; ++j) {
        float v = fmaxf(acc[j] * rinv + bf2f((ushort)xv[j]) + bl[o8 * 8 + j], 0.f) * sinv;
        ov[j] = (short)f2bf(v);
    }
    *(bf16x8*)&r1s[(size_t)node * 128 + o8 * 8] = ov;
}

// ---------------- gather sum: g = bf16(sum of r1s rows) ----------------
__global__ void gather_sum(const ushort* __restrict__ src,
                           const int* __restrict__ off, const int* __restrict__ slist,
                           ushort* __restrict__ dst) {
    int gt = blockIdx.x * 256 + threadIdx.x;
    int node = gt >> 4;
    if (node >= N_ORIG) return;
    int o8 = gt & 15;
    int s = off[node], e = off[node + 1];
    float acc[8] = {0.f, 0.f, 0.f, 0.f, 0.f, 0.f, 0.f, 0.f};
    for (int i = s; i < e; ++i) {
        int sn = slist[i];
        bf16x8 v = *(const bf16x8*)&src[(size_t)sn * 128 + o8 * 8];
        #pragma unroll
        for (int j = 0; j < 8; ++j) acc[j] += bf2f((ushort)v[j]);
    }
    bf16x8 ov;
    #pragma unroll
    for (int j = 0; j < 8; ++j) ov[j] = (short)f2bf(acc[j]);
    *(bf16x8*)&dst[(size_t)node * 128 + o8 * 8] = ov;
}

extern "C" void kernel_launch(void* const* d_in, const int* in_sizes, int n_in,
                              void* d_out, int out_size, void* d_ws, size_t ws_size,
                              hipStream_t stream) {
    const float* x_ret    = (const float*)d_in[0];
    const float* x_orig   = (const float*)d_in[1];
    const int*   ret_idx  = (const int*)d_in[2];
    const int*   orig_idx = (const int*)d_in[3];
    const float* Wl1  = (const float*)d_in[6];
    const float* bl1  = (const float*)d_in[7];
    const float* Wr1  = (const float*)d_in[8];
    const float* Wg2  = (const float*)d_in[9];
    const float* bg2  = (const float*)d_in[10];
    const float* Wout = (const float*)d_in[14];
    const float* bout = (const float*)d_in[15];
    float* out = (float*)d_out;

    // workspace layout (16B-aligned regions first)
    ushort* hoB  = (ushort*)d_ws;                       // 100k*128 bf16 (h_o, later g)
    ushort* xrB  = hoB + (size_t)N_ORIG * 128;          // 200k*128 bf16 (xr, later t)
    ushort* r1sB = xrB + (size_t)N_RET * 128;           // 200k*128 bf16
    ushort* wtl1 = r1sB + (size_t)N_RET * 128;          // 16384
    ushort* wtr1 = wtl1 + 16384;                        // 16384
    ushort* wtg2 = wtr1 + 16384;                        // 16384
    ushort* wto  = wtg2 + 16384;                        // 8192
    int* off_ret  = (int*)(wto + 8192);                 // N_RET+1
    int* off_orig = off_ret + N_RET + 1;                // N_ORIG+1
    int* bcnt1    = off_orig + N_ORIG + 1;              // 512
    int* bcnt2    = bcnt1 + 512;                        // 512  (adjacent: one memset)
    int* boff1    = bcnt2 + 512;                        // 512
    int* boff2    = boff1 + 512;                        // 512
    int* bcur1    = boff2 + 512;                        // 512
    int* bcur2    = bcur1 + 512;                        // 512
    int* el1      = bcur2 + 512;                        // N_EDGE (src=orig, grouped by ret)
    int* el2      = el1 + N_EDGE;                       // N_EDGE (src=ret, grouped by orig)
    int* binned1  = el2 + N_EDGE;                       // N_EDGE packed
    int* binned2  = binned1 + N_EDGE;                   // N_EDGE packed

    // weights -> transposed bf16
    wt_kernel<<<64, 256, 0, stream>>>(Wl1,  wtl1, 16384, 7);
    wt_kernel<<<64, 256, 0, stream>>>(Wr1,  wtr1, 16384, 7);
    wt_kernel<<<64, 256, 0, stream>>>(Wg2,  wtg2, 16384, 7);
    wt_kernel<<<32, 256, 0, stream>>>(Wout, wto,  8192,  6);

    // CSR build: bucket counts -> bucket scan -> bin -> per-bucket fill (+ node offsets)
    hipMemsetAsync(bcnt1, 0, 1024 * sizeof(int), stream);
    const int nbin_blocks = (N_EDGE + 8191) / 8192;
    bucket_count<<<nbin_blocks, 256, 0, stream>>>(ret_idx, orig_idx, bcnt1, bcnt2);
    scan_buckets<<<1, 256, 0, stream>>>(bcnt1, boff1, bcur1, bcnt2, boff2, bcur2,
                                        off_ret, off_orig);
    bin_kernel<<<nbin_blocks, 256, 0, stream>>>(ret_idx, orig_idx, bcur1, binned1, NB_RET);
    bin_kernel<<<nbin_blocks, 256, 0, stream>>>(orig_idx, ret_idx, bcur2, binned2, NB_ORIG);
    fill2_kernel<<<NB_RET,  256, 0, stream>>>(binned1, boff1, off_ret,  el1, N_RET);
    fill2_kernel<<<NB_ORIG, 256, 0, stream>>>(binned2, boff2, off_orig, el2, N_ORIG);

    // h_o = bf16(x_orig @ Wl1)            [100k x 128]
    gemm_k<128, false, 0><<<(N_ORIG + 63) / 64, 256, 0, stream>>>(
        x_orig, wtl1, nullptr, nullptr, hoB, N_ORIG);
    // xr = bf16(x_ret @ Wr1)              [200k x 128]
    gemm_k<128, false, 0><<<(N_RET + 63) / 64, 256, 0, stream>>>(
        x_ret, wtr1, nullptr, nullptr, xrB, N_RET);

    // r1s = bf16(relu(mean_agg(h_o) + xr + bl1) * inv_s)   [200k x 128]
    gather_sage<<<(N_RET * 16) / 256, 256, 0, stream>>>(hoB, xrB, off_ret, el1, bl1, r1sB);

    // g = bf16(segment_sum(r1s))          [100k x 128]  (reuses hoB)
    gather_sum<<<(N_ORIG * 16) / 256, 256, 0, stream>>>(r1sB, off_orig, el2, hoB);

    // t = bf16(relu((g @ Wg2) * inv_d + bg2))   [100k x 128]  (reuses xrB)
    gemm_k<128, true, 1><<<(N_ORIG + 63) / 64, 256, 0, stream>>>(
        hoB, wtg2, off_orig, bg2, xrB, N_ORIG);

    // out = (t @ Wout) + bout             [100k x 64] f32
    gemm_k<64, true, 2><<<(N_ORIG + 63) / 64, 256, 0, stream>>>(
        xrB, wto, nullptr, bout, out, N_ORIG);
}